// Round 9
// baseline (135.453 us; speedup 1.0000x reference)
//
#include <hip/hip_runtime.h>
#include <hip/hip_fp16.h>
#include <hip/hip_bf16.h>
#include <cstddef>
#include <cstdint>

#define SNL_N 50000
#define SNL_K 32
#define SNL_D 128
#define SNL_EPS 1e-12f
#define ROWS_PB 25
#define NBLK 2000          // ~15KB LDS -> 8 blocks/CU (wave-capped) -> all co-resident
#define NPASS 4
#define BUCKET 12500       // fp16 bucket = 3.2 MB < 4 MiB L2/XCD
#define NITEM (ROWS_PB * SNL_K)   // 800 items/block; code fits 10 bits
#define YIPAD 136          // yi LDS row pitch in halves
#define WS_NORM_OFF 16384
#define WS_GH_OFF (16384 + 204800)

// ---------------- fp16 quant + per-row norm pre-pass ------------------------
// One wave per 2 rows: lane = h*32 + c. Norms computed from the ROUNDED
// halves so d2 = ni + nj - 2*dot is consistent with the fp16 data.
__global__ __launch_bounds__(256) void snl_quant(const float* __restrict__ emb,
                                                 __half* __restrict__ gh,
                                                 float* __restrict__ gnorm) {
    const int tid  = threadIdx.x;
    const int lane = tid & 63;
    const int wid  = tid >> 6;
    const int h    = lane >> 5;
    const int c    = lane & 31;
    const int row  = (blockIdx.x * 4 + wid) * 2 + h;   // 6250 blocks x 8 rows
    const float4 v = reinterpret_cast<const float4*>(emb)[(size_t)row * 32 + c];
    __half2 h0 = __floats2half2_rn(v.x, v.y);
    __half2 h1 = __floats2half2_rn(v.z, v.w);
    uint2 pk;
    pk.x = *reinterpret_cast<unsigned int*>(&h0);
    pk.y = *reinterpret_cast<unsigned int*>(&h1);
    reinterpret_cast<uint2*>(gh)[(size_t)row * 32 + c] = pk;
    const float2 f0 = __half22float2(h0), f1 = __half22float2(h1);
    float nrm = f0.x * f0.x + f0.y * f0.y + f1.x * f1.x + f1.y * f1.y;
#pragma unroll
    for (int off = 1; off < 32; off <<= 1) nrm += __shfl_xor(nrm, off, 64);
    if (c == 0) gnorm[row] = nrm;
}

__device__ __forceinline__ float dot2acc(__half2 a, __half2 b, float c) {
#if __has_builtin(__builtin_amdgcn_fdot2)
    return __builtin_amdgcn_fdot2(a, b, c, false);
#else
    float2 fa = __half22float2(a), fb = __half22float2(b);
    c = fmaf(fa.x, fb.x, c);
    return fmaf(fa.y, fb.y, c);
#endif
}

// ---------------- main bucketed-pass kernel ---------------------------------
// r8 structure (2000 co-resident blocks, self-paced lockstep bucket passes) +
// NPASS 8->4 (step-quantization waste 22%->11%), norm-trick inner loop (8
// fdot2, no hsub2), and a 2-deep software pipeline across 32-item steps.
__global__ __launch_bounds__(256, 8) void snl_main_h(
    const __half* __restrict__ gh,
    const float* __restrict__ gnorm,
    const float* __restrict__ psim,
    const int* __restrict__ aidx,
    float* __restrict__ out,
    float* __restrict__ part)
{
    const int tid = threadIdx.x;
    const int b   = blockIdx.x;
    const int i0  = b * ROWS_PB;

    __shared__ __half         yib[ROWS_PB * YIPAD];  // 6800 B
    __shared__ float          nib[ROWS_PB];          //  100 B
    __shared__ float          d2b[NITEM];            // 3200 B
    __shared__ unsigned short idb[NITEM];            // 1600 B
    __shared__ unsigned int   lst[NITEM];            // 3200 B: (a<<10)|(r*32+k)
    __shared__ int cnt[NPASS], offs[NPASS + 1], wrk[NPASS];
    __shared__ float bred[4];

    const float4* gh4 = reinterpret_cast<const float4*>(gh);  // 16B = 8 halves

    // ---- stage yi chunks + row norms + ids ----
    for (int it = 0; it < 2; ++it) {
        const int idx = it * 256 + tid;
        if (idx < ROWS_PB * 16) {
            const int row = idx >> 4, c = idx & 15;
            *reinterpret_cast<float4*>(&yib[row * YIPAD + c * 8]) =
                gh4[(size_t)(i0 + row) * 16 + c];
        }
    }
    if (tid < ROWS_PB) nib[tid] = gnorm[i0 + tid];
    for (int it = 0; it < 4; ++it) {
        const int idx = it * 256 + tid;
        if (idx < NITEM)
            idb[idx] = (unsigned short)aidx[(size_t)i0 * SNL_K + idx];
    }
    if (tid < NPASS) cnt[tid] = 0;
    __syncthreads();

    // ---- counting sort by bucket(anchor), anchor fused into entry ----
    for (int it = 0; it < 4; ++it) {
        const int idx = it * 256 + tid;
        if (idx < NITEM) atomicAdd(&cnt[idb[idx] / BUCKET], 1);
    }
    __syncthreads();
    if (tid == 0) {
        int acc = 0;
        for (int p = 0; p < NPASS; ++p) { offs[p] = acc; wrk[p] = acc; acc += cnt[p]; }
        offs[NPASS] = acc;
    }
    __syncthreads();
    for (int it = 0; it < 4; ++it) {
        const int idx = it * 256 + tid;
        if (idx < NITEM) {
            const unsigned a = idb[idx];
            lst[atomicAdd(&wrk[a / BUCKET], 1)] = (a << 10) | (unsigned)idx;
        }
    }
    __syncthreads();

    // ---- self-paced bucket passes ----
    const int oct  = tid >> 3;   // item slot in a 32-item step
    const int dc   = tid & 7;    // 16B chunk; 8 lanes = one 256B fp16 row
    const int xsub = b >> 3;     // 0..249: slice within my XCD group (b%8 ~ XCD)
    float pf = 0.0f;

#pragma unroll 1
    for (int p = 0; p < NPASS; ++p) {
        // prefetch my XCD-group's 50-row slice of bucket p (250 blocks x 50
        // rows = 12500 = full bucket) + its norm slice
        const int prow = p * BUCKET + xsub * 50;
        const size_t pbase = (size_t)prow * 16;
        for (int it = 0; it < 4; ++it) {
            const int idx = it * 256 + tid;
            if (idx < 50 * 16) pf += gh4[pbase + idx].x;
        }
        if (tid < 50) pf += gnorm[prow + tid];

        // dense processing of this block's in-bucket items, 2-deep pipelined
        const int s0 = offs[p], s1 = offs[p + 1];
        if (s1 > s0) {
            // prologue: load step-0 item (clamped)
            unsigned e = lst[min(s0 + oct, s1 - 1)];
            int code = (int)(e & 1023u);
            int r    = code >> 5;
            int a    = (int)(e >> 10);
            const float4* jr = gh4 + (size_t)a * 16;
            float4 gj0 = jr[dc], gj1 = jr[dc + 8];
            float  njv = gnorm[a];
            float4 yi0 = *reinterpret_cast<const float4*>(&yib[r * YIPAD + dc * 8]);
            float4 yi1 = *reinterpret_cast<const float4*>(&yib[r * YIPAD + (dc + 8) * 8]);

            for (int base = s0; base < s1; base += 32) {
                const bool hasnext = (base + 32) < s1;   // block-uniform
                int code2 = 0, r2 = 0, a2 = 0;
                float4 ngj0 = {}, ngj1 = {}, nyi0 = {}, nyi1 = {};
                float nnjv = 0.0f;
                if (hasnext) {
                    const unsigned e2 = lst[min(base + 32 + oct, s1 - 1)];
                    code2 = (int)(e2 & 1023u);
                    r2    = code2 >> 5;
                    a2    = (int)(e2 >> 10);
                    const float4* jr2 = gh4 + (size_t)a2 * 16;
                    ngj0 = jr2[dc]; ngj1 = jr2[dc + 8];
                    nnjv = gnorm[a2];
                    nyi0 = *reinterpret_cast<const float4*>(&yib[r2 * YIPAD + dc * 8]);
                    nyi1 = *reinterpret_cast<const float4*>(&yib[r2 * YIPAD + (dc + 8) * 8]);
                }
                // compute current: dot only (norm trick)
                float acc = 0.0f;
                const __half2* hj0 = reinterpret_cast<const __half2*>(&gj0);
                const __half2* hj1 = reinterpret_cast<const __half2*>(&gj1);
                const __half2* hi0 = reinterpret_cast<const __half2*>(&yi0);
                const __half2* hi1 = reinterpret_cast<const __half2*>(&yi1);
#pragma unroll
                for (int u = 0; u < 4; ++u) acc = dot2acc(hi0[u], hj0[u], acc);
#pragma unroll
                for (int u = 0; u < 4; ++u) acc = dot2acc(hi1[u], hj1[u], acc);
                acc += __shfl_xor(acc, 1, 64);
                acc += __shfl_xor(acc, 2, 64);
                acc += __shfl_xor(acc, 4, 64);
                const float d2v = nib[r] + njv - 2.0f * acc;
                if (dc == 0 && base + oct < s1) d2b[code] = d2v;
                // shift pipeline
                code = code2; r = r2; njv = nnjv;
                gj0 = ngj0; gj1 = ngj1; yi0 = nyi0; yi1 = nyi1;
                (void)a2;
            }
        }
    }
    __syncthreads();

    // ---- softmax + outputs (one wave per row, round-robin) ----
    const int wid  = tid >> 6;
    const int lane = tid & 63;
    float loss_acc = 0.0f;
    for (int r = wid; r < ROWS_PB; r += 4) {
        const int i = i0 + r;
        const float d2 = d2b[r * SNL_K + (lane & 31)];
        const float s = -d2;
        float m = s;
#pragma unroll
        for (int off = 1; off < 32; off <<= 1)
            m = fmaxf(m, __shfl_xor(m, off, 64));
        const float e = __expf(s - m);
        float ss = e;
#pragma unroll
        for (int off = 1; off < 32; off <<= 1)
            ss += __shfl_xor(ss, off, 64);
        const float logq = (s - m) - __logf(ss);
        const float q = e / ss;
        if (lane < SNL_K) {
            out[1 + (size_t)i * SNL_K + lane] = q;
            const float pv = psim[(size_t)i * SNL_K + lane];
            loss_acc += pv * (__logf(pv + SNL_EPS) - logq);
        }
    }

    __asm__ volatile("" :: "v"(pf));   // keep prefetch loads alive

#pragma unroll
    for (int off = 1; off < 64; off <<= 1)
        loss_acc += __shfl_xor(loss_acc, off, 64);
    if (lane == 0) bred[wid] = loss_acc;
    __syncthreads();
    if (tid == 0) part[b] = bred[0] + bred[1] + bred[2] + bred[3];
}

// ---------------- fallback: fp32 kernel (if ws too small) -------------------
#define F32_ROWS 50
#define F32_NBLK 1000
#define F32_NPASS 8
#define F32_BUCKET 6250
__global__ __launch_bounds__(256, 4) void snl_main_f32(
    const float* __restrict__ emb,
    const float* __restrict__ psim,
    const int* __restrict__ aidx,
    float* __restrict__ out,
    float* __restrict__ part)
{
    const int tid = threadIdx.x;
    const int b   = blockIdx.x;
    const int i0  = b * F32_ROWS;

    __shared__ float          yib[F32_ROWS * SNL_D];
    __shared__ float          d2b[F32_ROWS * SNL_K];
    __shared__ unsigned short idb[F32_ROWS * SNL_K];
    __shared__ unsigned short lst[F32_ROWS * SNL_K];
    __shared__ int cnt[F32_NPASS], offs[F32_NPASS + 1], wrk[F32_NPASS];
    __shared__ float bred[4];

    const float4* emb4 = reinterpret_cast<const float4*>(emb);

    for (int it = 0; it < 7; ++it) {
        const int idx = it * 256 + tid;
        if (idx < F32_ROWS * SNL_D / 4)
            reinterpret_cast<float4*>(yib)[idx] = emb4[(size_t)i0 * (SNL_D / 4) + idx];
        if (idx < F32_ROWS * SNL_K)
            idb[idx] = (unsigned short)aidx[(size_t)i0 * SNL_K + idx];
    }
    if (tid < F32_NPASS) cnt[tid] = 0;
    __syncthreads();
    for (int it = 0; it < 7; ++it) {
        const int idx = it * 256 + tid;
        if (idx < F32_ROWS * SNL_K) atomicAdd(&cnt[idb[idx] / F32_BUCKET], 1);
    }
    __syncthreads();
    if (tid == 0) {
        int acc = 0;
        for (int p = 0; p < F32_NPASS; ++p) { offs[p] = acc; wrk[p] = acc; acc += cnt[p]; }
        offs[F32_NPASS] = acc;
    }
    __syncthreads();
    for (int it = 0; it < 7; ++it) {
        const int idx = it * 256 + tid;
        if (idx < F32_ROWS * SNL_K) {
            const int p = idb[idx] / F32_BUCKET;
            lst[atomicAdd(&wrk[p], 1)] = (unsigned short)idx;
        }
    }
    __syncthreads();

    const int oct  = tid >> 3;
    const int dc   = tid & 7;
    const int xsub = b >> 3;
    float pf = 0.0f;

#pragma unroll 1
    for (int p = 0; p < F32_NPASS; ++p) {
        const size_t pbase4 = ((size_t)p * F32_BUCKET + (size_t)xsub * 50) * (SNL_D / 4);
        for (int it = 0; it < 7; ++it) {
            const int idx = it * 256 + tid;
            if (idx < 50 * SNL_D / 4) pf += emb4[pbase4 + idx].x;
        }
        const int s0 = offs[p], s1 = offs[p + 1];
        for (int base = s0; base < s1; base += 32) {
            const int item = base + oct;
            if (item < s1) {
                const int code = (int)lst[item];
                const int r = code >> 5;
                const int a = (int)idb[code];
                const float4* jr = emb4 + (size_t)a * (SNL_D / 4);
                float acc = 0.0f;
#pragma unroll
                for (int it = 0; it < 4; ++it) {
                    const float4 yj = jr[dc + it * 8];
                    const float4 yi =
                        reinterpret_cast<const float4*>(yib)[r * (SNL_D / 4) + dc + it * 8];
                    const float dx = yi.x - yj.x;
                    const float dy = yi.y - yj.y;
                    const float dz = yi.z - yj.z;
                    const float dw = yi.w - yj.w;
                    acc = fmaf(dx, dx, acc);
                    acc = fmaf(dy, dy, acc);
                    acc = fmaf(dz, dz, acc);
                    acc = fmaf(dw, dw, acc);
                }
                acc += __shfl_xor(acc, 1, 64);
                acc += __shfl_xor(acc, 2, 64);
                acc += __shfl_xor(acc, 4, 64);
                if (dc == 0) d2b[code] = acc;
            }
        }
    }
    __syncthreads();

    const int wid  = tid >> 6;
    const int lane = tid & 63;
    float loss_acc = 0.0f;
    for (int r = wid; r < F32_ROWS; r += 4) {
        const int i = i0 + r;
        const float d2 = d2b[r * SNL_K + (lane & 31)];
        const float s = -d2;
        float m = s;
#pragma unroll
        for (int off = 1; off < 32; off <<= 1)
            m = fmaxf(m, __shfl_xor(m, off, 64));
        const float e = __expf(s - m);
        float ss = e;
#pragma unroll
        for (int off = 1; off < 32; off <<= 1)
            ss += __shfl_xor(ss, off, 64);
        const float logq = (s - m) - __logf(ss);
        const float q = e / ss;
        if (lane < SNL_K) {
            out[1 + (size_t)i * SNL_K + lane] = q;
            const float pv = psim[(size_t)i * SNL_K + lane];
            loss_acc += pv * (__logf(pv + SNL_EPS) - logq);
        }
    }
    __asm__ volatile("" :: "v"(pf));
#pragma unroll
    for (int off = 1; off < 64; off <<= 1)
        loss_acc += __shfl_xor(loss_acc, off, 64);
    if (lane == 0) bred[wid] = loss_acc;
    __syncthreads();
    if (tid == 0) part[b] = bred[0] + bred[1] + bred[2] + bred[3];
}

__global__ __launch_bounds__(256) void snl_loss_reduce(const float* __restrict__ part,
                                                       int npart,
                                                       float* __restrict__ out) {
    double acc = 0.0;
    for (int i = threadIdx.x; i < npart; i += 256) acc += (double)part[i];
#pragma unroll
    for (int off = 1; off < 64; off <<= 1)
        acc += __shfl_xor(acc, off, 64);
    __shared__ double sred[4];
    if ((threadIdx.x & 63) == 0) sred[threadIdx.x >> 6] = acc;
    __syncthreads();
    if (threadIdx.x == 0)
        out[0] = (float)((sred[0] + sred[1] + sred[2] + sred[3]) / (double)SNL_N);
}

extern "C" void kernel_launch(void* const* d_in, const int* in_sizes, int n_in,
                              void* d_out, int out_size, void* d_ws, size_t ws_size,
                              hipStream_t stream) {
    const float* emb  = (const float*)d_in[0];
    const float* psim = (const float*)d_in[1];
    const int*   aidx = (const int*)d_in[2];
    float* out  = (float*)d_out;
    float* part = (float*)d_ws;   // first 8 KB (NBLK floats)

    const size_t need = (size_t)WS_GH_OFF + (size_t)SNL_N * SNL_D * sizeof(__half);
    if (ws_size >= need) {
        float*  gnorm = (float*)((char*)d_ws + WS_NORM_OFF);
        __half* gh    = (__half*)((char*)d_ws + WS_GH_OFF);
        snl_quant<<<SNL_N / 8, 256, 0, stream>>>(emb, gh, gnorm);
        snl_main_h<<<NBLK, 256, 0, stream>>>(gh, gnorm, psim, aidx, out, part);
        snl_loss_reduce<<<1, 256, 0, stream>>>(part, NBLK, out);
    } else {
        snl_main_f32<<<F32_NBLK, 256, 0, stream>>>(emb, psim, aidx, out, part);
        snl_loss_reduce<<<1, 256, 0, stream>>>(part, F32_NBLK, out);
    }
}